// Round 1
// baseline (5995.925 us; speedup 1.0000x reference)
//
#include <hip/hip_runtime.h>

// ---------------------------------------------------------------------------
// JK-SAGE forward, fp32 baseline.
//   agg = segment_mean(x[src], dst);  h = relu(agg@Wl + x@Wr + b)   (x2 layers)
//   out = h1 @ Wo[:128] + h2 @ Wo[128:] + b_out
// Twin (detached) stream in the reference is dead code for the output.
// ---------------------------------------------------------------------------

// Fused degree-count + feature scatter. 32 threads per edge, float4 per thread.
__global__ __launch_bounds__(256)
void scatter_feat(const float4* __restrict__ xf4, const int* __restrict__ src,
                  const int* __restrict__ dst, float* __restrict__ agg,
                  float* __restrict__ cnt, int E) {
    int gid  = blockIdx.x * blockDim.x + threadIdx.x;
    int e    = gid >> 5;
    int lane = gid & 31;
    if (e >= E) return;
    int s = src[e];
    int d = dst[e];
    if (lane == 0) atomicAdd(&cnt[d], 1.0f);
    float4 v = xf4[(size_t)s * 32 + lane];
    float* o = agg + (size_t)d * 128 + lane * 4;
    atomicAdd(o + 0, v.x);
    atomicAdd(o + 1, v.y);
    atomicAdd(o + 2, v.z);
    atomicAdd(o + 3, v.w);
}

// H[n][0:128] = relu( (Aagg[n]/max(cnt[n],1)) @ Wl + X[n] @ Wr + bias )
// Tile: 64 rows x 128 cols per block, 256 threads, 4x8 microtile, BK=16.
__global__ __launch_bounds__(256)
void sage_gemm(const float* __restrict__ Aagg, const float* __restrict__ cnt,
               const float* __restrict__ X,
               const float* __restrict__ Wl, const float* __restrict__ Wr,
               const float* __restrict__ bias, float* __restrict__ H, int N) {
    __shared__ float As[16][68];    // A-tile transposed [k][m], +4 pad
    __shared__ float Bs[16][132];   // B-tile [k][col], +4 pad

    const int t  = threadIdx.x;
    const int tx = t & 15;          // col group: cols tx*8 .. tx*8+7
    const int ty = t >> 4;          // row group: rows ty*4 .. ty*4+3
    const int base = blockIdx.x * 64;

    float acc[4][8];
#pragma unroll
    for (int i = 0; i < 4; ++i)
#pragma unroll
        for (int j = 0; j < 8; ++j) acc[i][j] = 0.0f;

    // A-load mapping: thread -> (row m_a, k-quad k4)
    const int m_a    = t >> 2;
    const int k4     = t & 3;
    const int node_a = base + m_a;
    float sc = 1.0f;
    if (node_a < N) sc = 1.0f / fmaxf(cnt[node_a], 1.0f);

    for (int phase = 0; phase < 2; ++phase) {
        const float* Asrc = (phase == 0) ? Aagg : X;
        const float* Bsrc = (phase == 0) ? Wl : Wr;
        for (int kb = 0; kb < 128; kb += 16) {
            // ---- global loads into registers
            float4 av = make_float4(0.f, 0.f, 0.f, 0.f);
            if (node_a < N) {
                av = *(const float4*)(Asrc + (size_t)node_a * 128 + kb + k4 * 4);
                if (phase == 0) { av.x *= sc; av.y *= sc; av.z *= sc; av.w *= sc; }
            }
            const int f0 = t, f1 = t + 256;   // 512 float4s of B-tile
            float4 bv0 = *(const float4*)(Bsrc + (size_t)(kb + (f0 >> 5)) * 128 + (f0 & 31) * 4);
            float4 bv1 = *(const float4*)(Bsrc + (size_t)(kb + (f1 >> 5)) * 128 + (f1 & 31) * 4);

            __syncthreads();   // previous compute done before overwriting LDS
            As[k4 * 4 + 0][m_a] = av.x;
            As[k4 * 4 + 1][m_a] = av.y;
            As[k4 * 4 + 2][m_a] = av.z;
            As[k4 * 4 + 3][m_a] = av.w;
            *(float4*)&Bs[f0 >> 5][(f0 & 31) * 4] = bv0;
            *(float4*)&Bs[f1 >> 5][(f1 & 31) * 4] = bv1;
            __syncthreads();

            // ---- compute
#pragma unroll
            for (int kk = 0; kk < 16; ++kk) {
                float4 a  = *(const float4*)&As[kk][ty * 4];
                float4 b0 = *(const float4*)&Bs[kk][tx * 8];
                float4 b1 = *(const float4*)&Bs[kk][tx * 8 + 4];
                float ar[4] = {a.x, a.y, a.z, a.w};
                float br[8] = {b0.x, b0.y, b0.z, b0.w, b1.x, b1.y, b1.z, b1.w};
#pragma unroll
                for (int i = 0; i < 4; ++i)
#pragma unroll
                    for (int j = 0; j < 8; ++j) acc[i][j] += ar[i] * br[j];
            }
        }
    }

    // ---- epilogue: bias + relu + store
    float bcol[8];
#pragma unroll
    for (int j = 0; j < 8; ++j) bcol[j] = bias[tx * 8 + j];
#pragma unroll
    for (int i = 0; i < 4; ++i) {
        int node = base + ty * 4 + i;
        if (node < N) {
            float4 r0, r1;
            r0.x = fmaxf(acc[i][0] + bcol[0], 0.f);
            r0.y = fmaxf(acc[i][1] + bcol[1], 0.f);
            r0.z = fmaxf(acc[i][2] + bcol[2], 0.f);
            r0.w = fmaxf(acc[i][3] + bcol[3], 0.f);
            r1.x = fmaxf(acc[i][4] + bcol[4], 0.f);
            r1.y = fmaxf(acc[i][5] + bcol[5], 0.f);
            r1.z = fmaxf(acc[i][6] + bcol[6], 0.f);
            r1.w = fmaxf(acc[i][7] + bcol[7], 0.f);
            *(float4*)(H + (size_t)node * 128 + tx * 8)     = r0;
            *(float4*)(H + (size_t)node * 128 + tx * 8 + 4) = r1;
        }
    }
}

// out[n][c] = b_out[c] + sum_k h1[n][k]*Wo[k][c] + h2[n][k]*Wo[128+k][c]
// One block = 32 nodes; Wo (256x40) and 32 h-rows staged in LDS.
__global__ __launch_bounds__(256)
void out_gemm(const float* __restrict__ H1, const float* __restrict__ H2,
              const float* __restrict__ Wo, const float* __restrict__ bo,
              float* __restrict__ out, int N) {
    __shared__ float w_lds[256 * 40];
    __shared__ float h_lds[32][256];
    __shared__ float b_lds[40];

    const int t = threadIdx.x;
    for (int i = t; i < 256 * 40; i += 256) w_lds[i] = Wo[i];
    if (t < 40) b_lds[t] = bo[t];

    const int base = blockIdx.x * 32;
    for (int f = t; f < 1024; f += 256) {
        int node = f >> 5, c4 = f & 31;
        int gn = base + node;
        if (gn < N) {
            *(float4*)&h_lds[node][c4 * 4]       = *(const float4*)(H1 + (size_t)gn * 128 + c4 * 4);
            *(float4*)&h_lds[node][128 + c4 * 4] = *(const float4*)(H2 + (size_t)gn * 128 + c4 * 4);
        }
    }
    __syncthreads();

    for (int oid = t; oid < 32 * 40; oid += 256) {
        int node = oid / 40, col = oid % 40;
        int gn = base + node;
        if (gn >= N) continue;
        float acc = b_lds[col];
        const float* hp = h_lds[node];
#pragma unroll 8
        for (int k = 0; k < 256; ++k) acc += hp[k] * w_lds[k * 40 + col];
        out[(size_t)gn * 40 + col] = acc;
    }
}

extern "C" void kernel_launch(void* const* d_in, const int* in_sizes, int n_in,
                              void* d_out, int out_size, void* d_ws, size_t ws_size,
                              hipStream_t stream) {
    const float* x     = (const float*)d_in[0];
    const int*   ei1   = (const int*)d_in[1];
    const int*   ei2   = (const int*)d_in[2];
    const float* wl1   = (const float*)d_in[3];
    const float* wr1   = (const float*)d_in[4];
    const float* b1    = (const float*)d_in[5];
    const float* wl2   = (const float*)d_in[6];
    const float* wr2   = (const float*)d_in[7];
    const float* b2    = (const float*)d_in[8];
    const float* w_out = (const float*)d_in[9];
    const float* b_out = (const float*)d_in[10];

    const int N = in_sizes[0] / 128;
    const int E = in_sizes[1] / 2;
    const int* src1 = ei1;
    const int* dst1 = ei1 + E;
    const int* src2 = ei2;
    const int* dst2 = ei2 + E;

    // workspace layout (fp32): agg[N*128] | cnt[N] | h1[N*128] | h2[N*128]
    float* agg = (float*)d_ws;
    float* cnt = agg + (size_t)N * 128;
    float* h1  = cnt + N;
    float* h2  = h1 + (size_t)N * 128;
    const size_t zero_bytes = ((size_t)N * 128 + N) * sizeof(float);

    const int scatter_blocks = (int)(((size_t)E * 32 + 255) / 256);
    const int gemm_blocks    = (N + 63) / 64;
    const int out_blocks     = (N + 31) / 32;

    // ---- layer 1
    hipMemsetAsync(agg, 0, zero_bytes, stream);
    scatter_feat<<<scatter_blocks, 256, 0, stream>>>((const float4*)x, src1, dst1, agg, cnt, E);
    sage_gemm<<<gemm_blocks, 256, 0, stream>>>(agg, cnt, x, wl1, wr1, b1, h1, N);

    // ---- layer 2
    hipMemsetAsync(agg, 0, zero_bytes, stream);
    scatter_feat<<<scatter_blocks, 256, 0, stream>>>((const float4*)h1, src2, dst2, agg, cnt, E);
    sage_gemm<<<gemm_blocks, 256, 0, stream>>>(agg, cnt, h1, wl2, wr2, b2, h2, N);

    // ---- JK concat + output projection
    out_gemm<<<out_blocks, 256, 0, stream>>>(h1, h2, w_out, b_out, (float*)d_out, N);
}

// Round 2
// 1027.354 us; speedup vs baseline: 5.8363x; 5.8363x over previous
//
#include <hip/hip_runtime.h>

// ---------------------------------------------------------------------------
// JK-SAGE forward, fp32, CSR-gather aggregation (no feature atomics).
//   per layer: build CSR (hist + scan + fill) -> gather-mean -> fused GEMM
//   out = h1 @ Wo[:128] + h2 @ Wo[128:] + b_out
// agg scratch aliases h2 (each GEMM block reads its own A rows before its
// epilogue writes the same rows -> safe; Aagg/H params are NOT __restrict__).
// ---------------------------------------------------------------------------

__global__ __launch_bounds__(256)
void degree_hist(const int* __restrict__ dst, int* __restrict__ deg, int E) {
    int e = blockIdx.x * 256 + threadIdx.x;
    if (e < E) atomicAdd(&deg[dst[e]], 1);
}

// exclusive scan, stage 1: 1024 elems/block (256 thr x 4)
__global__ __launch_bounds__(256)
void scan1(const int* __restrict__ in, int* __restrict__ out,
           int* __restrict__ bsum, int N) {
    __shared__ int lds[256];
    const int t = threadIdx.x;
    const int base = blockIdx.x * 1024 + t * 4;
    int v[4], s = 0;
#pragma unroll
    for (int i = 0; i < 4; ++i) {
        v[i] = (base + i < N) ? in[base + i] : 0;
        s += v[i];
    }
    lds[t] = s;
    __syncthreads();
    for (int off = 1; off < 256; off <<= 1) {
        int y = (t >= off) ? lds[t - off] : 0;
        __syncthreads();
        lds[t] += y;
        __syncthreads();
    }
    int run = lds[t] - s;   // exclusive prefix for this thread
#pragma unroll
    for (int i = 0; i < 4; ++i) {
        if (base + i < N) out[base + i] = run;
        run += v[i];
    }
    if (t == 255) bsum[blockIdx.x] = lds[255];
}

// stage 2: single block scans block sums (any nb, chunked by 256)
__global__ __launch_bounds__(256)
void scan2(int* __restrict__ bsum, int nb) {
    __shared__ int lds[256];
    __shared__ int carry_s;
    const int t = threadIdx.x;
    if (t == 0) carry_s = 0;
    __syncthreads();
    for (int beg = 0; beg < nb; beg += 256) {
        int v = (beg + t < nb) ? bsum[beg + t] : 0;
        lds[t] = v;
        __syncthreads();
        for (int off = 1; off < 256; off <<= 1) {
            int y = (t >= off) ? lds[t - off] : 0;
            __syncthreads();
            lds[t] += y;
            __syncthreads();
        }
        int incl = lds[t];
        int carry = carry_s;
        if (beg + t < nb) bsum[beg + t] = carry + incl - v;  // exclusive
        __syncthreads();
        if (t == 255) carry_s = carry + incl;
        __syncthreads();
    }
}

// stage 3: add block offsets; row_ptr[N] = E
__global__ __launch_bounds__(256)
void scan3(int* __restrict__ row_ptr, const int* __restrict__ bsum, int N, int E) {
    int i = blockIdx.x * 256 + threadIdx.x;
    if (i < N) row_ptr[i] += bsum[i >> 10];
    if (i == 0) row_ptr[N] = E;
}

__global__ __launch_bounds__(256)
void csr_fill(const int* __restrict__ src, const int* __restrict__ dst,
              const int* __restrict__ row_ptr, int* __restrict__ fill,
              int* __restrict__ col, int E) {
    int e = blockIdx.x * 256 + threadIdx.x;
    if (e < E) {
        int d = dst[e];
        int p = row_ptr[d] + atomicAdd(&fill[d], 1);
        col[p] = src[e];
    }
}

// agg[n] = mean of x[col[row_ptr[n]..row_ptr[n+1])]; 32 lanes/node, float4/lane
__global__ __launch_bounds__(256)
void gather_mean(const float4* __restrict__ xf4, const int* __restrict__ row_ptr,
                 const int* __restrict__ col, float4* __restrict__ agg, int N) {
    int gid  = blockIdx.x * 256 + threadIdx.x;
    int node = gid >> 5;
    int lane = gid & 31;
    if (node >= N) return;
    int beg = row_ptr[node], end = row_ptr[node + 1];
    float4 acc = make_float4(0.f, 0.f, 0.f, 0.f);
    int e = beg;
    for (; e + 1 < end; e += 2) {   // 2 independent loads in flight
        int s0 = col[e], s1 = col[e + 1];
        float4 v0 = xf4[(size_t)s0 * 32 + lane];
        float4 v1 = xf4[(size_t)s1 * 32 + lane];
        acc.x += v0.x + v1.x; acc.y += v0.y + v1.y;
        acc.z += v0.z + v1.z; acc.w += v0.w + v1.w;
    }
    if (e < end) {
        int s0 = col[e];
        float4 v0 = xf4[(size_t)s0 * 32 + lane];
        acc.x += v0.x; acc.y += v0.y; acc.z += v0.z; acc.w += v0.w;
    }
    float inv = 1.0f / fmaxf((float)(end - beg), 1.0f);
    acc.x *= inv; acc.y *= inv; acc.z *= inv; acc.w *= inv;
    agg[(size_t)node * 32 + lane] = acc;
}

// H[n] = relu(Aagg[n] @ Wl + X[n] @ Wr + bias); 64x128 tile, 4x8 microtile.
// NOTE: Aagg and H may alias (agg scratch == h2) -> no __restrict__ on them.
__global__ __launch_bounds__(256)
void sage_gemm(const float* Aagg, const float* __restrict__ X,
               const float* __restrict__ Wl, const float* __restrict__ Wr,
               const float* __restrict__ bias, float* H, int N) {
    __shared__ float As[16][68];
    __shared__ float Bs[16][132];

    const int t  = threadIdx.x;
    const int tx = t & 15;
    const int ty = t >> 4;
    const int base = blockIdx.x * 64;

    float acc[4][8];
#pragma unroll
    for (int i = 0; i < 4; ++i)
#pragma unroll
        for (int j = 0; j < 8; ++j) acc[i][j] = 0.0f;

    const int m_a    = t >> 2;
    const int k4     = t & 3;
    const int node_a = base + m_a;

    for (int phase = 0; phase < 2; ++phase) {
        const float* Asrc = (phase == 0) ? Aagg : X;
        const float* Bsrc = (phase == 0) ? Wl : Wr;
        for (int kb = 0; kb < 128; kb += 16) {
            float4 av = make_float4(0.f, 0.f, 0.f, 0.f);
            if (node_a < N)
                av = *(const float4*)(Asrc + (size_t)node_a * 128 + kb + k4 * 4);
            const int f0 = t, f1 = t + 256;
            float4 bv0 = *(const float4*)(Bsrc + (size_t)(kb + (f0 >> 5)) * 128 + (f0 & 31) * 4);
            float4 bv1 = *(const float4*)(Bsrc + (size_t)(kb + (f1 >> 5)) * 128 + (f1 & 31) * 4);

            __syncthreads();
            As[k4 * 4 + 0][m_a] = av.x;
            As[k4 * 4 + 1][m_a] = av.y;
            As[k4 * 4 + 2][m_a] = av.z;
            As[k4 * 4 + 3][m_a] = av.w;
            *(float4*)&Bs[f0 >> 5][(f0 & 31) * 4] = bv0;
            *(float4*)&Bs[f1 >> 5][(f1 & 31) * 4] = bv1;
            __syncthreads();

#pragma unroll
            for (int kk = 0; kk < 16; ++kk) {
                float4 a  = *(const float4*)&As[kk][ty * 4];
                float4 b0 = *(const float4*)&Bs[kk][tx * 8];
                float4 b1 = *(const float4*)&Bs[kk][tx * 8 + 4];
                float ar[4] = {a.x, a.y, a.z, a.w};
                float br[8] = {b0.x, b0.y, b0.z, b0.w, b1.x, b1.y, b1.z, b1.w};
#pragma unroll
                for (int i = 0; i < 4; ++i)
#pragma unroll
                    for (int j = 0; j < 8; ++j) acc[i][j] += ar[i] * br[j];
            }
        }
    }

    float bcol[8];
#pragma unroll
    for (int j = 0; j < 8; ++j) bcol[j] = bias[tx * 8 + j];
#pragma unroll
    for (int i = 0; i < 4; ++i) {
        int node = base + ty * 4 + i;
        if (node < N) {
            float4 r0, r1;
            r0.x = fmaxf(acc[i][0] + bcol[0], 0.f);
            r0.y = fmaxf(acc[i][1] + bcol[1], 0.f);
            r0.z = fmaxf(acc[i][2] + bcol[2], 0.f);
            r0.w = fmaxf(acc[i][3] + bcol[3], 0.f);
            r1.x = fmaxf(acc[i][4] + bcol[4], 0.f);
            r1.y = fmaxf(acc[i][5] + bcol[5], 0.f);
            r1.z = fmaxf(acc[i][6] + bcol[6], 0.f);
            r1.w = fmaxf(acc[i][7] + bcol[7], 0.f);
            *(float4*)(H + (size_t)node * 128 + tx * 8)     = r0;
            *(float4*)(H + (size_t)node * 128 + tx * 8 + 4) = r1;
        }
    }
}

__global__ __launch_bounds__(256)
void out_gemm(const float* __restrict__ H1, const float* __restrict__ H2,
              const float* __restrict__ Wo, const float* __restrict__ bo,
              float* __restrict__ out, int N) {
    __shared__ float w_lds[256 * 40];
    __shared__ float h_lds[32][256];
    __shared__ float b_lds[40];

    const int t = threadIdx.x;
    for (int i = t; i < 256 * 40; i += 256) w_lds[i] = Wo[i];
    if (t < 40) b_lds[t] = bo[t];

    const int base = blockIdx.x * 32;
    for (int f = t; f < 1024; f += 256) {
        int node = f >> 5, c4 = f & 31;
        int gn = base + node;
        if (gn < N) {
            *(float4*)&h_lds[node][c4 * 4]       = *(const float4*)(H1 + (size_t)gn * 128 + c4 * 4);
            *(float4*)&h_lds[node][128 + c4 * 4] = *(const float4*)(H2 + (size_t)gn * 128 + c4 * 4);
        }
    }
    __syncthreads();

    for (int oid = t; oid < 32 * 40; oid += 256) {
        int node = oid / 40, col = oid % 40;
        int gn = base + node;
        if (gn >= N) continue;
        float acc = b_lds[col];
        const float* hp = h_lds[node];
#pragma unroll 8
        for (int k = 0; k < 256; ++k) acc += hp[k] * w_lds[k * 40 + col];
        out[(size_t)gn * 40 + col] = acc;
    }
}

extern "C" void kernel_launch(void* const* d_in, const int* in_sizes, int n_in,
                              void* d_out, int out_size, void* d_ws, size_t ws_size,
                              hipStream_t stream) {
    const float* x     = (const float*)d_in[0];
    const int*   ei1   = (const int*)d_in[1];
    const int*   ei2   = (const int*)d_in[2];
    const float* wl1   = (const float*)d_in[3];
    const float* wr1   = (const float*)d_in[4];
    const float* b1    = (const float*)d_in[5];
    const float* wl2   = (const float*)d_in[6];
    const float* wr2   = (const float*)d_in[7];
    const float* b2    = (const float*)d_in[8];
    const float* w_out = (const float*)d_in[9];
    const float* b_out = (const float*)d_in[10];

    const int N = in_sizes[0] / 128;
    const int E = in_sizes[1] / 2;

    // ---- workspace layout (reused across layers; 16B-aligned float region)
    int* deg     = (int*)d_ws;            // N
    int* fill    = deg + N;               // N
    int* row_ptr = fill + N;              // N+1
    int* bsum    = row_ptr + (N + 1);     // up to 256
    int* col     = bsum + 256;            // E
    size_t int_cnt = (size_t)(3 * N + 1 + 256) + (size_t)E;
    int_cnt = (int_cnt + 3) & ~(size_t)3;             // align to 16 B
    float* h1  = (float*)d_ws + int_cnt;              // N*128
    float* h2  = h1 + (size_t)N * 128;                // N*128 (doubles as agg)
    float* agg = h2;

    const int nb          = (N + 1023) / 1024;        // scan1 blocks
    const int edge_blocks = (E + 255) / 256;
    const int node_blocks = (N + 255) / 256;
    const int gath_blocks = (int)(((size_t)N * 32 + 255) / 256);
    const int gemm_blocks = (N + 63) / 64;
    const int out_blocks  = (N + 31) / 32;

    for (int layer = 0; layer < 2; ++layer) {
        const int*   ei   = (layer == 0) ? ei1 : ei2;
        const float* xin  = (layer == 0) ? x : h1;
        const float* Wl   = (layer == 0) ? wl1 : wl2;
        const float* Wr   = (layer == 0) ? wr1 : wr2;
        const float* bb   = (layer == 0) ? b1 : b2;
        float*       hout = (layer == 0) ? h1 : h2;
        const int* srcp = ei;
        const int* dstp = ei + E;

        hipMemsetAsync(deg, 0, (size_t)2 * N * sizeof(int), stream);  // deg+fill
        degree_hist<<<edge_blocks, 256, 0, stream>>>(dstp, deg, E);
        scan1<<<nb, 256, 0, stream>>>(deg, row_ptr, bsum, N);
        scan2<<<1, 256, 0, stream>>>(bsum, nb);
        scan3<<<node_blocks, 256, 0, stream>>>(row_ptr, bsum, N, E);
        csr_fill<<<edge_blocks, 256, 0, stream>>>(srcp, dstp, row_ptr, fill, col, E);
        gather_mean<<<gath_blocks, 256, 0, stream>>>((const float4*)xin, row_ptr, col,
                                                     (float4*)agg, N);
        sage_gemm<<<gemm_blocks, 256, 0, stream>>>(agg, xin, Wl, Wr, bb, hout, N);
    }

    out_gemm<<<out_blocks, 256, 0, stream>>>(h1, h2, w_out, b_out, (float*)d_out, N);
}

// Round 3
// 899.857 us; speedup vs baseline: 6.6632x; 1.1417x over previous
//
#include <hip/hip_runtime.h>

// ---------------------------------------------------------------------------
// JK-SAGE forward, fp32, CSR-gather aggregation (no feature atomics).
//   per layer: build CSR (hist + scan + fill) -> gather-mean -> fused GEMM
//   out = h1 @ Wo[:128] + h2 @ Wo[128:] + b_out
// agg scratch aliases h2 (each GEMM block reads its own A rows before its
// epilogue writes the same rows -> safe; Aagg/H params are NOT __restrict__).
// ---------------------------------------------------------------------------

__global__ __launch_bounds__(256)
void degree_hist(const int* __restrict__ dst, int* __restrict__ deg, int E) {
    int e = blockIdx.x * 256 + threadIdx.x;
    if (e < E) atomicAdd(&deg[dst[e]], 1);
}

// exclusive scan, stage 1: 1024 elems/block (256 thr x 4)
__global__ __launch_bounds__(256)
void scan1(const int* __restrict__ in, int* __restrict__ out,
           int* __restrict__ bsum, int N) {
    __shared__ int lds[256];
    const int t = threadIdx.x;
    const int base = blockIdx.x * 1024 + t * 4;
    int v[4], s = 0;
#pragma unroll
    for (int i = 0; i < 4; ++i) {
        v[i] = (base + i < N) ? in[base + i] : 0;
        s += v[i];
    }
    lds[t] = s;
    __syncthreads();
    for (int off = 1; off < 256; off <<= 1) {
        int y = (t >= off) ? lds[t - off] : 0;
        __syncthreads();
        lds[t] += y;
        __syncthreads();
    }
    int run = lds[t] - s;   // exclusive prefix for this thread
#pragma unroll
    for (int i = 0; i < 4; ++i) {
        if (base + i < N) out[base + i] = run;
        run += v[i];
    }
    if (t == 255) bsum[blockIdx.x] = lds[255];
}

// stage 2: single block scans block sums (any nb, chunked by 256)
__global__ __launch_bounds__(256)
void scan2(int* __restrict__ bsum, int nb) {
    __shared__ int lds[256];
    __shared__ int carry_s;
    const int t = threadIdx.x;
    if (t == 0) carry_s = 0;
    __syncthreads();
    for (int beg = 0; beg < nb; beg += 256) {
        int v = (beg + t < nb) ? bsum[beg + t] : 0;
        lds[t] = v;
        __syncthreads();
        for (int off = 1; off < 256; off <<= 1) {
            int y = (t >= off) ? lds[t - off] : 0;
            __syncthreads();
            lds[t] += y;
            __syncthreads();
        }
        int incl = lds[t];
        int carry = carry_s;
        if (beg + t < nb) bsum[beg + t] = carry + incl - v;  // exclusive
        __syncthreads();
        if (t == 255) carry_s = carry + incl;
        __syncthreads();
    }
}

// stage 3: add block offsets; row_ptr[N] = E
__global__ __launch_bounds__(256)
void scan3(int* __restrict__ row_ptr, const int* __restrict__ bsum, int N, int E) {
    int i = blockIdx.x * 256 + threadIdx.x;
    if (i < N) row_ptr[i] += bsum[i >> 10];
    if (i == 0) row_ptr[N] = E;
}

__global__ __launch_bounds__(256)
void csr_fill(const int* __restrict__ src, const int* __restrict__ dst,
              const int* __restrict__ row_ptr, int* __restrict__ fill,
              int* __restrict__ col, int E) {
    int e = blockIdx.x * 256 + threadIdx.x;
    if (e < E) {
        int d = dst[e];
        int p = row_ptr[d] + atomicAdd(&fill[d], 1);
        col[p] = src[e];
    }
}

// agg[n] = mean of x[col[row_ptr[n]..row_ptr[n+1])]; 32 lanes/node, float4/lane
__global__ __launch_bounds__(256)
void gather_mean(const float4* __restrict__ xf4, const int* __restrict__ row_ptr,
                 const int* __restrict__ col, float4* __restrict__ agg, int N) {
    int gid  = blockIdx.x * 256 + threadIdx.x;
    int node = gid >> 5;
    int lane = gid & 31;
    if (node >= N) return;
    int beg = row_ptr[node], end = row_ptr[node + 1];
    float4 acc = make_float4(0.f, 0.f, 0.f, 0.f);
    int e = beg;
    for (; e + 3 < end; e += 4) {   // 4 independent loads in flight
        int s0 = col[e], s1 = col[e + 1], s2 = col[e + 2], s3 = col[e + 3];
        float4 v0 = xf4[(size_t)s0 * 32 + lane];
        float4 v1 = xf4[(size_t)s1 * 32 + lane];
        float4 v2 = xf4[(size_t)s2 * 32 + lane];
        float4 v3 = xf4[(size_t)s3 * 32 + lane];
        acc.x += (v0.x + v1.x) + (v2.x + v3.x);
        acc.y += (v0.y + v1.y) + (v2.y + v3.y);
        acc.z += (v0.z + v1.z) + (v2.z + v3.z);
        acc.w += (v0.w + v1.w) + (v2.w + v3.w);
    }
    for (; e < end; ++e) {
        int s0 = col[e];
        float4 v0 = xf4[(size_t)s0 * 32 + lane];
        acc.x += v0.x; acc.y += v0.y; acc.z += v0.z; acc.w += v0.w;
    }
    float inv = 1.0f / fmaxf((float)(end - beg), 1.0f);
    acc.x *= inv; acc.y *= inv; acc.z *= inv; acc.w *= inv;
    agg[(size_t)node * 32 + lane] = acc;
}

// H[n] = relu(Aagg[n] @ Wl + X[n] @ Wr + bias); 64x128 tile, 4x8 microtile.
// NOTE: Aagg and H may alias (agg scratch == h2) -> no __restrict__ on them.
__global__ __launch_bounds__(256)
void sage_gemm(const float* Aagg, const float* __restrict__ X,
               const float* __restrict__ Wl, const float* __restrict__ Wr,
               const float* __restrict__ bias, float* H, int N) {
    __shared__ float As[16][68];
    __shared__ float Bs[16][132];

    const int t  = threadIdx.x;
    const int tx = t & 15;
    const int ty = t >> 4;
    const int base = blockIdx.x * 64;

    float acc[4][8];
#pragma unroll
    for (int i = 0; i < 4; ++i)
#pragma unroll
        for (int j = 0; j < 8; ++j) acc[i][j] = 0.0f;

    const int m_a    = t >> 2;
    const int k4     = t & 3;
    const int node_a = base + m_a;

    for (int phase = 0; phase < 2; ++phase) {
        const float* Asrc = (phase == 0) ? Aagg : X;
        const float* Bsrc = (phase == 0) ? Wl : Wr;
        for (int kb = 0; kb < 128; kb += 16) {
            float4 av = make_float4(0.f, 0.f, 0.f, 0.f);
            if (node_a < N)
                av = *(const float4*)(Asrc + (size_t)node_a * 128 + kb + k4 * 4);
            const int f0 = t, f1 = t + 256;
            float4 bv0 = *(const float4*)(Bsrc + (size_t)(kb + (f0 >> 5)) * 128 + (f0 & 31) * 4);
            float4 bv1 = *(const float4*)(Bsrc + (size_t)(kb + (f1 >> 5)) * 128 + (f1 & 31) * 4);

            __syncthreads();
            As[k4 * 4 + 0][m_a] = av.x;
            As[k4 * 4 + 1][m_a] = av.y;
            As[k4 * 4 + 2][m_a] = av.z;
            As[k4 * 4 + 3][m_a] = av.w;
            *(float4*)&Bs[f0 >> 5][(f0 & 31) * 4] = bv0;
            *(float4*)&Bs[f1 >> 5][(f1 & 31) * 4] = bv1;
            __syncthreads();

#pragma unroll
            for (int kk = 0; kk < 16; ++kk) {
                float4 a  = *(const float4*)&As[kk][ty * 4];
                float4 b0 = *(const float4*)&Bs[kk][tx * 8];
                float4 b1 = *(const float4*)&Bs[kk][tx * 8 + 4];
                float ar[4] = {a.x, a.y, a.z, a.w};
                float br[8] = {b0.x, b0.y, b0.z, b0.w, b1.x, b1.y, b1.z, b1.w};
#pragma unroll
                for (int i = 0; i < 4; ++i)
#pragma unroll
                    for (int j = 0; j < 8; ++j) acc[i][j] += ar[i] * br[j];
            }
        }
    }

    float bcol[8];
#pragma unroll
    for (int j = 0; j < 8; ++j) bcol[j] = bias[tx * 8 + j];
#pragma unroll
    for (int i = 0; i < 4; ++i) {
        int node = base + ty * 4 + i;
        if (node < N) {
            float4 r0, r1;
            r0.x = fmaxf(acc[i][0] + bcol[0], 0.f);
            r0.y = fmaxf(acc[i][1] + bcol[1], 0.f);
            r0.z = fmaxf(acc[i][2] + bcol[2], 0.f);
            r0.w = fmaxf(acc[i][3] + bcol[3], 0.f);
            r1.x = fmaxf(acc[i][4] + bcol[4], 0.f);
            r1.y = fmaxf(acc[i][5] + bcol[5], 0.f);
            r1.z = fmaxf(acc[i][6] + bcol[6], 0.f);
            r1.w = fmaxf(acc[i][7] + bcol[7], 0.f);
            *(float4*)(H + (size_t)node * 128 + tx * 8)     = r0;
            *(float4*)(H + (size_t)node * 128 + tx * 8 + 4) = r1;
        }
    }
}

// out[n][c] = b_out[c] + sum_k h1[n][k]*Wo[k][c] + h2[n][k]*Wo[128+k][c]
// Register-tiled: 128 nodes x 40 cols per block, 256 thr, 4x5 microtile,
// K=256 streamed in 16-chunks. A transposed in LDS (2-way alias only),
// B-chunk reads are 8-bank broadcast -> conflict-free.
__global__ __launch_bounds__(256)
void out_gemm(const float* __restrict__ H1, const float* __restrict__ H2,
              const float* __restrict__ Wo, const float* __restrict__ bo,
              float* __restrict__ out, int N) {
    __shared__ float As[16][132];   // [k][node], +4 pad
    __shared__ float Bs[16][40];    // Wo chunk [k][col]

    const int t  = threadIdx.x;
    const int tx = t & 7;           // col group: cols tx*5 .. tx*5+4
    const int ty = t >> 3;          // row group: rows ty*4 .. ty*4+3 (0..31)
    const int base = blockIdx.x * 128;

    float acc[4][5];
#pragma unroll
    for (int i = 0; i < 4; ++i)
#pragma unroll
        for (int j = 0; j < 5; ++j) acc[i][j] = 0.0f;

    for (int src = 0; src < 2; ++src) {
        const float* Hsrc = (src == 0) ? H1 : H2;
        for (int kb = 0; kb < 128; kb += 16) {
            // ---- global loads: A = 512 float4s (2/thread), B = 160 float4s
            float4 av[2];
#pragma unroll
            for (int i = 0; i < 2; ++i) {
                int f = t + i * 256;
                int row = f >> 2, q = f & 3;
                int node = base + row;
                av[i] = (node < N)
                    ? *(const float4*)(Hsrc + (size_t)node * 128 + kb + q * 4)
                    : make_float4(0.f, 0.f, 0.f, 0.f);
            }
            float4 bv = make_float4(0.f, 0.f, 0.f, 0.f);
            int bk = 0, bc = 0;
            if (t < 160) {
                bk = t / 10; bc = t % 10;
                bv = *(const float4*)(Wo + (size_t)(src * 128 + kb + bk) * 40 + bc * 4);
            }

            __syncthreads();
#pragma unroll
            for (int i = 0; i < 2; ++i) {
                int f = t + i * 256;
                int row = f >> 2, q = f & 3;
                As[q * 4 + 0][row] = av[i].x;
                As[q * 4 + 1][row] = av[i].y;
                As[q * 4 + 2][row] = av[i].z;
                As[q * 4 + 3][row] = av[i].w;
            }
            if (t < 160) *(float4*)&Bs[bk][bc * 4] = bv;
            __syncthreads();

            // ---- compute
#pragma unroll
            for (int kk = 0; kk < 16; ++kk) {
                float4 a = *(const float4*)&As[kk][ty * 4];
                float b[5];
#pragma unroll
                for (int j = 0; j < 5; ++j) b[j] = Bs[kk][tx * 5 + j];
                float ar[4] = {a.x, a.y, a.z, a.w};
#pragma unroll
                for (int i = 0; i < 4; ++i)
#pragma unroll
                    for (int j = 0; j < 5; ++j) acc[i][j] += ar[i] * b[j];
            }
        }
    }

    // ---- epilogue
    float bc5[5];
#pragma unroll
    for (int j = 0; j < 5; ++j) bc5[j] = bo[tx * 5 + j];
#pragma unroll
    for (int i = 0; i < 4; ++i) {
        int node = base + ty * 4 + i;
        if (node < N) {
#pragma unroll
            for (int j = 0; j < 5; ++j)
                out[(size_t)node * 40 + tx * 5 + j] = acc[i][j] + bc5[j];
        }
    }
}

extern "C" void kernel_launch(void* const* d_in, const int* in_sizes, int n_in,
                              void* d_out, int out_size, void* d_ws, size_t ws_size,
                              hipStream_t stream) {
    const float* x     = (const float*)d_in[0];
    const int*   ei1   = (const int*)d_in[1];
    const int*   ei2   = (const int*)d_in[2];
    const float* wl1   = (const float*)d_in[3];
    const float* wr1   = (const float*)d_in[4];
    const float* b1    = (const float*)d_in[5];
    const float* wl2   = (const float*)d_in[6];
    const float* wr2   = (const float*)d_in[7];
    const float* b2    = (const float*)d_in[8];
    const float* w_out = (const float*)d_in[9];
    const float* b_out = (const float*)d_in[10];

    const int N = in_sizes[0] / 128;
    const int E = in_sizes[1] / 2;

    // ---- workspace layout (reused across layers; 16B-aligned float region)
    int* deg     = (int*)d_ws;            // N
    int* fill    = deg + N;               // N
    int* row_ptr = fill + N;              // N+1
    int* bsum    = row_ptr + (N + 1);     // up to 256
    int* col     = bsum + 256;            // E
    size_t int_cnt = (size_t)(3 * N + 1 + 256) + (size_t)E;
    int_cnt = (int_cnt + 3) & ~(size_t)3;             // align to 16 B
    float* h1  = (float*)d_ws + int_cnt;              // N*128
    float* h2  = h1 + (size_t)N * 128;                // N*128 (doubles as agg)
    float* agg = h2;

    const int nb          = (N + 1023) / 1024;        // scan1 blocks
    const int edge_blocks = (E + 255) / 256;
    const int node_blocks = (N + 255) / 256;
    const int gath_blocks = (int)(((size_t)N * 32 + 255) / 256);
    const int gemm_blocks = (N + 63) / 64;
    const int out_blocks  = (N + 127) / 128;

    for (int layer = 0; layer < 2; ++layer) {
        const int*   ei   = (layer == 0) ? ei1 : ei2;
        const float* xin  = (layer == 0) ? x : h1;
        const float* Wl   = (layer == 0) ? wl1 : wl2;
        const float* Wr   = (layer == 0) ? wr1 : wr2;
        const float* bb   = (layer == 0) ? b1 : b2;
        float*       hout = (layer == 0) ? h1 : h2;
        const int* srcp = ei;
        const int* dstp = ei + E;

        hipMemsetAsync(deg, 0, (size_t)2 * N * sizeof(int), stream);  // deg+fill
        degree_hist<<<edge_blocks, 256, 0, stream>>>(dstp, deg, E);
        scan1<<<nb, 256, 0, stream>>>(deg, row_ptr, bsum, N);
        scan2<<<1, 256, 0, stream>>>(bsum, nb);
        scan3<<<node_blocks, 256, 0, stream>>>(row_ptr, bsum, N, E);
        csr_fill<<<edge_blocks, 256, 0, stream>>>(srcp, dstp, row_ptr, fill, col, E);
        gather_mean<<<gath_blocks, 256, 0, stream>>>((const float4*)xin, row_ptr, col,
                                                     (float4*)agg, N);
        sage_gemm<<<gemm_blocks, 256, 0, stream>>>(agg, xin, Wl, Wr, bb, hout, N);
    }

    out_gemm<<<out_blocks, 256, 0, stream>>>(h1, h2, w_out, b_out, (float*)d_out, N);
}

// Round 4
// 819.549 us; speedup vs baseline: 7.3161x; 1.0980x over previous
//
#include <hip/hip_runtime.h>

// ---------------------------------------------------------------------------
// JK-SAGE forward. CSR-gather aggregation; features stored bf16 at kernel
// boundaries (x, h1, h2, agg), all arithmetic fp32. Weights stay fp32.
//   per layer: build CSR -> gather-mean (bf16 in/out) -> fused GEMM (bf16 A,
//   fp32 W, bf16 out) ; out = h1 @ Wo[:128] + h2 @ Wo[128:] + b_out (fp32)
// ---------------------------------------------------------------------------

__device__ __forceinline__ unsigned short f2b(float f) {
    unsigned u = __float_as_uint(f);
    unsigned r = (u + 0x7fffu + ((u >> 16) & 1u)) >> 16;   // RNE
    return (unsigned short)r;
}
__device__ __forceinline__ float b2f(unsigned short b) {
    return __uint_as_float((unsigned)b << 16);
}
__device__ __forceinline__ float lo2f(unsigned u) { return __uint_as_float(u << 16); }
__device__ __forceinline__ float hi2f(unsigned u) { return __uint_as_float(u & 0xffff0000u); }
__device__ __forceinline__ unsigned pack2(float a, float b) {
    return (unsigned)f2b(a) | ((unsigned)f2b(b) << 16);
}

// ---- one-time x fp32 -> bf16 (8 elems/thread)
__global__ __launch_bounds__(256)
void cast_f32_b16(const float4* __restrict__ src, uint4* __restrict__ dst, long n8) {
    long i = (long)blockIdx.x * 256 + threadIdx.x;
    if (i >= n8) return;
    float4 a = src[i * 2];
    float4 b = src[i * 2 + 1];
    uint4 o;
    o.x = pack2(a.x, a.y); o.y = pack2(a.z, a.w);
    o.z = pack2(b.x, b.y); o.w = pack2(b.z, b.w);
    dst[i] = o;
}

__global__ __launch_bounds__(256)
void degree_hist(const int* __restrict__ dst, int* __restrict__ deg, int E) {
    int e = blockIdx.x * 256 + threadIdx.x;
    if (e < E) atomicAdd(&deg[dst[e]], 1);
}

// exclusive scan, stage 1: 1024 elems/block (256 thr x 4)
__global__ __launch_bounds__(256)
void scan1(const int* __restrict__ in, int* __restrict__ out,
           int* __restrict__ bsum, int N) {
    __shared__ int lds[256];
    const int t = threadIdx.x;
    const int base = blockIdx.x * 1024 + t * 4;
    int v[4], s = 0;
#pragma unroll
    for (int i = 0; i < 4; ++i) {
        v[i] = (base + i < N) ? in[base + i] : 0;
        s += v[i];
    }
    lds[t] = s;
    __syncthreads();
    for (int off = 1; off < 256; off <<= 1) {
        int y = (t >= off) ? lds[t - off] : 0;
        __syncthreads();
        lds[t] += y;
        __syncthreads();
    }
    int run = lds[t] - s;
#pragma unroll
    for (int i = 0; i < 4; ++i) {
        if (base + i < N) out[base + i] = run;
        run += v[i];
    }
    if (t == 255) bsum[blockIdx.x] = lds[255];
}

__global__ __launch_bounds__(256)
void scan2(int* __restrict__ bsum, int nb) {
    __shared__ int lds[256];
    __shared__ int carry_s;
    const int t = threadIdx.x;
    if (t == 0) carry_s = 0;
    __syncthreads();
    for (int beg = 0; beg < nb; beg += 256) {
        int v = (beg + t < nb) ? bsum[beg + t] : 0;
        lds[t] = v;
        __syncthreads();
        for (int off = 1; off < 256; off <<= 1) {
            int y = (t >= off) ? lds[t - off] : 0;
            __syncthreads();
            lds[t] += y;
            __syncthreads();
        }
        int incl = lds[t];
        int carry = carry_s;
        if (beg + t < nb) bsum[beg + t] = carry + incl - v;
        __syncthreads();
        if (t == 255) carry_s = carry + incl;
        __syncthreads();
    }
}

__global__ __launch_bounds__(256)
void scan3(int* __restrict__ row_ptr, const int* __restrict__ bsum, int N, int E) {
    int i = blockIdx.x * 256 + threadIdx.x;
    if (i < N) row_ptr[i] += bsum[i >> 10];
    if (i == 0) row_ptr[N] = E;
}

__global__ __launch_bounds__(256)
void csr_fill(const int* __restrict__ src, const int* __restrict__ dst,
              const int* __restrict__ row_ptr, int* __restrict__ fill,
              int* __restrict__ col, int E) {
    int e = blockIdx.x * 256 + threadIdx.x;
    if (e < E) {
        int d = dst[e];
        int p = row_ptr[d] + atomicAdd(&fill[d], 1);
        col[p] = src[e];
    }
}

// agg[n] = mean of xb[col[...]] ; bf16 rows (16 uint4 per row), 16 lanes/node,
// each lane owns 8 features (one uint4). fp32 accumulate, bf16 out.
__global__ __launch_bounds__(256)
void gather_mean_b16(const uint4* __restrict__ xb, const int* __restrict__ row_ptr,
                     const int* __restrict__ col, uint4* __restrict__ agg, int N) {
    int gid  = blockIdx.x * 256 + threadIdx.x;
    int node = gid >> 4;
    int lane = gid & 15;
    if (node >= N) return;
    int beg = row_ptr[node], end = row_ptr[node + 1];
    float acc[8];
#pragma unroll
    for (int j = 0; j < 8; ++j) acc[j] = 0.0f;
    int e = beg;
    for (; e + 3 < end; e += 4) {
        int s0 = col[e], s1 = col[e + 1], s2 = col[e + 2], s3 = col[e + 3];
        uint4 v0 = xb[(size_t)s0 * 16 + lane];
        uint4 v1 = xb[(size_t)s1 * 16 + lane];
        uint4 v2 = xb[(size_t)s2 * 16 + lane];
        uint4 v3 = xb[(size_t)s3 * 16 + lane];
        acc[0] += (lo2f(v0.x) + lo2f(v1.x)) + (lo2f(v2.x) + lo2f(v3.x));
        acc[1] += (hi2f(v0.x) + hi2f(v1.x)) + (hi2f(v2.x) + hi2f(v3.x));
        acc[2] += (lo2f(v0.y) + lo2f(v1.y)) + (lo2f(v2.y) + lo2f(v3.y));
        acc[3] += (hi2f(v0.y) + hi2f(v1.y)) + (hi2f(v2.y) + hi2f(v3.y));
        acc[4] += (lo2f(v0.z) + lo2f(v1.z)) + (lo2f(v2.z) + lo2f(v3.z));
        acc[5] += (hi2f(v0.z) + hi2f(v1.z)) + (hi2f(v2.z) + hi2f(v3.z));
        acc[6] += (lo2f(v0.w) + lo2f(v1.w)) + (lo2f(v2.w) + lo2f(v3.w));
        acc[7] += (hi2f(v0.w) + hi2f(v1.w)) + (hi2f(v2.w) + hi2f(v3.w));
    }
    for (; e < end; ++e) {
        uint4 v0 = xb[(size_t)col[e] * 16 + lane];
        acc[0] += lo2f(v0.x); acc[1] += hi2f(v0.x);
        acc[2] += lo2f(v0.y); acc[3] += hi2f(v0.y);
        acc[4] += lo2f(v0.z); acc[5] += hi2f(v0.z);
        acc[6] += lo2f(v0.w); acc[7] += hi2f(v0.w);
    }
    float inv = 1.0f / fmaxf((float)(end - beg), 1.0f);
#pragma unroll
    for (int j = 0; j < 8; ++j) acc[j] *= inv;
    uint4 o;
    o.x = pack2(acc[0], acc[1]); o.y = pack2(acc[2], acc[3]);
    o.z = pack2(acc[4], acc[5]); o.w = pack2(acc[6], acc[7]);
    agg[(size_t)node * 16 + lane] = o;
}

// H[n] = relu(Agg[n]@Wl + X[n]@Wr + bias). A inputs bf16, W fp32, out bf16.
// 64 rows x 128 cols per block, 256 threads, 4x8 microtile, BK=16.
__global__ __launch_bounds__(256)
void sage_gemm_b16(const unsigned short* __restrict__ Aggb,
                   const unsigned short* __restrict__ Xb,
                   const float* __restrict__ Wl, const float* __restrict__ Wr,
                   const float* __restrict__ bias,
                   unsigned short* __restrict__ Hb, int N) {
    __shared__ float As[16][68];    // [k][m], +4 pad
    __shared__ float Bs[16][132];   // [k][col], +4 pad

    const int t  = threadIdx.x;
    const int tx = t & 15;
    const int ty = t >> 4;
    const int base = blockIdx.x * 64;

    float acc[4][8];
#pragma unroll
    for (int i = 0; i < 4; ++i)
#pragma unroll
        for (int j = 0; j < 8; ++j) acc[i][j] = 0.0f;

    const int m_a    = t >> 2;
    const int k4     = t & 3;
    const int node_a = base + m_a;

    for (int phase = 0; phase < 2; ++phase) {
        const unsigned short* Asrc = (phase == 0) ? Aggb : Xb;
        const float* Bsrc = (phase == 0) ? Wl : Wr;
        for (int kb = 0; kb < 128; kb += 16) {
            // A: 4 consecutive bf16 per thread (8 B)
            float a0 = 0.f, a1 = 0.f, a2 = 0.f, a3 = 0.f;
            if (node_a < N) {
                uint2 u = *(const uint2*)(Asrc + (size_t)node_a * 128 + kb + k4 * 4);
                a0 = lo2f(u.x); a1 = hi2f(u.x); a2 = lo2f(u.y); a3 = hi2f(u.y);
            }
            const int f0 = t, f1 = t + 256;
            float4 bv0 = *(const float4*)(Bsrc + (size_t)(kb + (f0 >> 5)) * 128 + (f0 & 31) * 4);
            float4 bv1 = *(const float4*)(Bsrc + (size_t)(kb + (f1 >> 5)) * 128 + (f1 & 31) * 4);

            __syncthreads();
            As[k4 * 4 + 0][m_a] = a0;
            As[k4 * 4 + 1][m_a] = a1;
            As[k4 * 4 + 2][m_a] = a2;
            As[k4 * 4 + 3][m_a] = a3;
            *(float4*)&Bs[f0 >> 5][(f0 & 31) * 4] = bv0;
            *(float4*)&Bs[f1 >> 5][(f1 & 31) * 4] = bv1;
            __syncthreads();

#pragma unroll
            for (int kk = 0; kk < 16; ++kk) {
                float4 a  = *(const float4*)&As[kk][ty * 4];
                float4 b0 = *(const float4*)&Bs[kk][tx * 8];
                float4 b1 = *(const float4*)&Bs[kk][tx * 8 + 4];
                float ar[4] = {a.x, a.y, a.z, a.w};
                float br[8] = {b0.x, b0.y, b0.z, b0.w, b1.x, b1.y, b1.z, b1.w};
#pragma unroll
                for (int i = 0; i < 4; ++i)
#pragma unroll
                    for (int j = 0; j < 8; ++j) acc[i][j] += ar[i] * br[j];
            }
        }
    }

    float bcol[8];
#pragma unroll
    for (int j = 0; j < 8; ++j) bcol[j] = bias[tx * 8 + j];
#pragma unroll
    for (int i = 0; i < 4; ++i) {
        int node = base + ty * 4 + i;
        if (node < N) {
            float r[8];
#pragma unroll
            for (int j = 0; j < 8; ++j) r[j] = fmaxf(acc[i][j] + bcol[j], 0.f);
            uint4 o;
            o.x = pack2(r[0], r[1]); o.y = pack2(r[2], r[3]);
            o.z = pack2(r[4], r[5]); o.w = pack2(r[6], r[7]);
            *(uint4*)(Hb + (size_t)node * 128 + tx * 8) = o;
        }
    }
}

// out[n][c] = b_out[c] + sum_k h1[n][k]*Wo[k][c] + h2[n][k]*Wo[128+k][c]
// 128 nodes x 40 cols per block, 4x5 microtile. H inputs bf16, Wo/out fp32.
__global__ __launch_bounds__(256)
void out_gemm_b16(const unsigned short* __restrict__ H1b,
                  const unsigned short* __restrict__ H2b,
                  const float* __restrict__ Wo, const float* __restrict__ bo,
                  float* __restrict__ out, int N) {
    __shared__ float As[16][132];   // [k][node], +4 pad
    __shared__ float Bs[16][40];    // Wo chunk [k][col]

    const int t  = threadIdx.x;
    const int tx = t & 7;
    const int ty = t >> 3;
    const int base = blockIdx.x * 128;

    float acc[4][5];
#pragma unroll
    for (int i = 0; i < 4; ++i)
#pragma unroll
        for (int j = 0; j < 5; ++j) acc[i][j] = 0.0f;

    for (int src = 0; src < 2; ++src) {
        const unsigned short* Hsrc = (src == 0) ? H1b : H2b;
        for (int kb = 0; kb < 128; kb += 16) {
            // A: 128 rows x 16 k bf16 = 256 x uint4 (8 bf16) -> 1/thread
            const int row  = t >> 1;
            const int half = t & 1;
            uint4 av = make_uint4(0, 0, 0, 0);
            int node = base + row;
            if (node < N)
                av = *(const uint4*)(Hsrc + (size_t)node * 128 + kb + half * 8);
            float4 bv = make_float4(0.f, 0.f, 0.f, 0.f);
            int bk = 0, bc = 0;
            if (t < 160) {
                bk = t / 10; bc = t % 10;
                bv = *(const float4*)(Wo + (size_t)(src * 128 + kb + bk) * 40 + bc * 4);
            }

            __syncthreads();
            {
                const int kbase = half * 8;
                As[kbase + 0][row] = lo2f(av.x);
                As[kbase + 1][row] = hi2f(av.x);
                As[kbase + 2][row] = lo2f(av.y);
                As[kbase + 3][row] = hi2f(av.y);
                As[kbase + 4][row] = lo2f(av.z);
                As[kbase + 5][row] = hi2f(av.z);
                As[kbase + 6][row] = lo2f(av.w);
                As[kbase + 7][row] = hi2f(av.w);
            }
            if (t < 160) *(float4*)&Bs[bk][bc * 4] = bv;
            __syncthreads();

#pragma unroll
            for (int kk = 0; kk < 16; ++kk) {
                float4 a = *(const float4*)&As[kk][ty * 4];
                float b[5];
#pragma unroll
                for (int j = 0; j < 5; ++j) b[j] = Bs[kk][tx * 5 + j];
                float ar[4] = {a.x, a.y, a.z, a.w};
#pragma unroll
                for (int i = 0; i < 4; ++i)
#pragma unroll
                    for (int j = 0; j < 5; ++j) acc[i][j] += ar[i] * b[j];
            }
        }
    }

    float bc5[5];
#pragma unroll
    for (int j = 0; j < 5; ++j) bc5[j] = bo[tx * 5 + j];
#pragma unroll
    for (int i = 0; i < 4; ++i) {
        int node = base + ty * 4 + i;
        if (node < N) {
#pragma unroll
            for (int j = 0; j < 5; ++j)
                out[(size_t)node * 40 + tx * 5 + j] = acc[i][j] + bc5[j];
        }
    }
}

extern "C" void kernel_launch(void* const* d_in, const int* in_sizes, int n_in,
                              void* d_out, int out_size, void* d_ws, size_t ws_size,
                              hipStream_t stream) {
    const float* x     = (const float*)d_in[0];
    const int*   ei1   = (const int*)d_in[1];
    const int*   ei2   = (const int*)d_in[2];
    const float* wl1   = (const float*)d_in[3];
    const float* wr1   = (const float*)d_in[4];
    const float* b1    = (const float*)d_in[5];
    const float* wl2   = (const float*)d_in[6];
    const float* wr2   = (const float*)d_in[7];
    const float* b2    = (const float*)d_in[8];
    const float* w_out = (const float*)d_in[9];
    const float* b_out = (const float*)d_in[10];

    const int N = in_sizes[0] / 128;
    const int E = in_sizes[1] / 2;

    // ---- workspace: int region | xb | h1b | h2b | aggb  (bf16 = ushort)
    int* deg     = (int*)d_ws;            // N
    int* fill    = deg + N;               // N
    int* row_ptr = fill + N;              // N+1
    int* bsum    = row_ptr + (N + 1);     // up to 256
    int* col     = bsum + 256;            // E
    size_t int_cnt = (size_t)(3 * N + 1 + 256) + (size_t)E;
    int_cnt = (int_cnt + 3) & ~(size_t)3;                 // 16 B align
    unsigned short* xb   = (unsigned short*)((int*)d_ws + int_cnt);
    unsigned short* h1b  = xb  + (size_t)N * 128;
    unsigned short* h2b  = h1b + (size_t)N * 128;
    unsigned short* aggb = h2b + (size_t)N * 128;

    const long n8         = (long)N * 128 / 8;
    const int cast_blocks = (int)((n8 + 255) / 256);
    const int nb          = (N + 1023) / 1024;
    const int edge_blocks = (E + 255) / 256;
    const int node_blocks = (N + 255) / 256;
    const int gath_blocks = (int)(((size_t)N * 16 + 255) / 256);
    const int gemm_blocks = (N + 63) / 64;
    const int out_blocks  = (N + 127) / 128;

    cast_f32_b16<<<cast_blocks, 256, 0, stream>>>((const float4*)x, (uint4*)xb, n8);

    for (int layer = 0; layer < 2; ++layer) {
        const int* ei = (layer == 0) ? ei1 : ei2;
        const unsigned short* xin = (layer == 0) ? xb : h1b;
        const float* Wl = (layer == 0) ? wl1 : wl2;
        const float* Wr = (layer == 0) ? wr1 : wr2;
        const float* bb = (layer == 0) ? b1 : b2;
        unsigned short* hout = (layer == 0) ? h1b : h2b;
        const int* srcp = ei;
        const int* dstp = ei + E;

        hipMemsetAsync(deg, 0, (size_t)2 * N * sizeof(int), stream);  // deg+fill
        degree_hist<<<edge_blocks, 256, 0, stream>>>(dstp, deg, E);
        scan1<<<nb, 256, 0, stream>>>(deg, row_ptr, bsum, N);
        scan2<<<1, 256, 0, stream>>>(bsum, nb);
        scan3<<<node_blocks, 256, 0, stream>>>(row_ptr, bsum, N, E);
        csr_fill<<<edge_blocks, 256, 0, stream>>>(srcp, dstp, row_ptr, fill, col, E);
        gather_mean_b16<<<gath_blocks, 256, 0, stream>>>((const uint4*)xin, row_ptr,
                                                         col, (uint4*)aggb, N);
        sage_gemm_b16<<<gemm_blocks, 256, 0, stream>>>(aggb, xin, Wl, Wr, bb, hout, N);
    }

    out_gemm_b16<<<out_blocks, 256, 0, stream>>>(h1b, h2b, w_out, b_out,
                                                 (float*)d_out, N);
}

// Round 5
// 713.470 us; speedup vs baseline: 8.4039x; 1.1487x over previous
//
#include <hip/hip_runtime.h>

// ---------------------------------------------------------------------------
// JK-SAGE forward. CSR-gather aggregation (bf16 features, fp32 accumulate),
// MFMA (bf16 16x16x32) GEMMs with fragment-order prepacked weights.
//   per layer: build CSR -> gather-mean -> MFMA GEMM (no LDS, no barriers)
//   out = h1 @ Wo[:128] + h2 @ Wo[128:] + b_out  (fp32 out)
// ---------------------------------------------------------------------------

typedef __attribute__((ext_vector_type(8))) short short8;
typedef __attribute__((ext_vector_type(4))) float floatx4;

__device__ __forceinline__ unsigned short f2b(float f) {
    unsigned u = __float_as_uint(f);
    unsigned r = (u + 0x7fffu + ((u >> 16) & 1u)) >> 16;   // RNE
    return (unsigned short)r;
}
__device__ __forceinline__ float lo2f(unsigned u) { return __uint_as_float(u << 16); }
__device__ __forceinline__ float hi2f(unsigned u) { return __uint_as_float(u & 0xffff0000u); }
__device__ __forceinline__ unsigned pack2(float a, float b) {
    return (unsigned)f2b(a) | ((unsigned)f2b(b) << 16);
}

// ---- one-time x fp32 -> bf16 (8 elems/thread)
__global__ __launch_bounds__(256)
void cast_f32_b16(const float4* __restrict__ src, uint4* __restrict__ dst, long n8) {
    long i = (long)blockIdx.x * 256 + threadIdx.x;
    if (i >= n8) return;
    float4 a = src[i * 2];
    float4 b = src[i * 2 + 1];
    uint4 o;
    o.x = pack2(a.x, a.y); o.y = pack2(a.z, a.w);
    o.z = pack2(b.x, b.y); o.w = pack2(b.z, b.w);
    dst[i] = o;
}

// ---- weight cast + repack into MFMA b-frag order.
// Layer Wt (per layer, 8 c_tiles): idx = ((c*8+kb)*64+lane)*8+j
//   k = kb*32 + (lane>>4)*8 + j ; n = c*16 + (lane&15)
//   v = k<128 ? Wl[k][n] : Wr[k-128][n]
// Wot (3 c_tiles): col = c*16+(lane&15); v = col<40 ? Wo[k][col] : 0
__global__ __launch_bounds__(256)
void prep_weights(const float* __restrict__ wl1, const float* __restrict__ wr1,
                  const float* __restrict__ wl2, const float* __restrict__ wr2,
                  const float* __restrict__ wo,
                  unsigned short* __restrict__ wt1, unsigned short* __restrict__ wt2,
                  unsigned short* __restrict__ wot) {
    int idx = blockIdx.x * 256 + threadIdx.x;
    if (idx < 65536) {   // two layer matrices, 32768 each
        int l = idx >> 15;
        int i = idx & 32767;
        int j = i & 7, lane = (i >> 3) & 63, kb = (i >> 9) & 7, c = i >> 12;
        int k = kb * 32 + (lane >> 4) * 8 + j;
        int n = c * 16 + (lane & 15);
        const float* Wl = l ? wl2 : wl1;
        const float* Wr = l ? wr2 : wr1;
        float v = (k < 128) ? Wl[k * 128 + n] : Wr[(k - 128) * 128 + n];
        (l ? wt2 : wt1)[i] = f2b(v);
    } else if (idx < 65536 + 12288) {
        int i = idx - 65536;
        int j = i & 7, lane = (i >> 3) & 63, kb = (i >> 9) & 7, c = i >> 12;
        int k = kb * 32 + (lane >> 4) * 8 + j;
        int col = c * 16 + (lane & 15);
        float v = (col < 40) ? wo[k * 40 + col] : 0.0f;
        wot[i] = f2b(v);
    }
}

__global__ __launch_bounds__(256)
void degree_hist(const int* __restrict__ dst, int* __restrict__ deg, int E) {
    int e = blockIdx.x * 256 + threadIdx.x;
    if (e < E) atomicAdd(&deg[dst[e]], 1);
}

// exclusive scan, stage 1: 1024 elems/block (256 thr x 4)
__global__ __launch_bounds__(256)
void scan1(const int* __restrict__ in, int* __restrict__ out,
           int* __restrict__ bsum, int N) {
    __shared__ int lds[256];
    const int t = threadIdx.x;
    const int base = blockIdx.x * 1024 + t * 4;
    int v[4], s = 0;
#pragma unroll
    for (int i = 0; i < 4; ++i) {
        v[i] = (base + i < N) ? in[base + i] : 0;
        s += v[i];
    }
    lds[t] = s;
    __syncthreads();
    for (int off = 1; off < 256; off <<= 1) {
        int y = (t >= off) ? lds[t - off] : 0;
        __syncthreads();
        lds[t] += y;
        __syncthreads();
    }
    int run = lds[t] - s;
#pragma unroll
    for (int i = 0; i < 4; ++i) {
        if (base + i < N) out[base + i] = run;
        run += v[i];
    }
    if (t == 255) bsum[blockIdx.x] = lds[255];
}

__global__ __launch_bounds__(256)
void scan2(int* __restrict__ bsum, int nb) {
    __shared__ int lds[256];
    __shared__ int carry_s;
    const int t = threadIdx.x;
    if (t == 0) carry_s = 0;
    __syncthreads();
    for (int beg = 0; beg < nb; beg += 256) {
        int v = (beg + t < nb) ? bsum[beg + t] : 0;
        lds[t] = v;
        __syncthreads();
        for (int off = 1; off < 256; off <<= 1) {
            int y = (t >= off) ? lds[t - off] : 0;
            __syncthreads();
            lds[t] += y;
            __syncthreads();
        }
        int incl = lds[t];
        int carry = carry_s;
        if (beg + t < nb) bsum[beg + t] = carry + incl - v;
        __syncthreads();
        if (t == 255) carry_s = carry + incl;
        __syncthreads();
    }
}

__global__ __launch_bounds__(256)
void scan3(int* __restrict__ row_ptr, const int* __restrict__ bsum, int N, int E) {
    int i = blockIdx.x * 256 + threadIdx.x;
    if (i < N) row_ptr[i] += bsum[i >> 10];
    if (i == 0) row_ptr[N] = E;
}

__global__ __launch_bounds__(256)
void csr_fill(const int* __restrict__ src, const int* __restrict__ dst,
              const int* __restrict__ row_ptr, int* __restrict__ fill,
              int* __restrict__ col, int E) {
    int e = blockIdx.x * 256 + threadIdx.x;
    if (e < E) {
        int d = dst[e];
        int p = row_ptr[d] + atomicAdd(&fill[d], 1);
        col[p] = src[e];
    }
}

// agg[n] = mean of xb[col[...]] ; bf16 rows (16 uint4/row), 16 lanes/node.
__global__ __launch_bounds__(256)
void gather_mean_b16(const uint4* __restrict__ xb, const int* __restrict__ row_ptr,
                     const int* __restrict__ col, uint4* __restrict__ agg, int N) {
    int gid  = blockIdx.x * 256 + threadIdx.x;
    int node = gid >> 4;
    int lane = gid & 15;
    if (node >= N) return;
    int beg = row_ptr[node], end = row_ptr[node + 1];
    float acc[8];
#pragma unroll
    for (int j = 0; j < 8; ++j) acc[j] = 0.0f;
    int e = beg;
    for (; e + 3 < end; e += 4) {
        int s0 = col[e], s1 = col[e + 1], s2 = col[e + 2], s3 = col[e + 3];
        uint4 v0 = xb[(size_t)s0 * 16 + lane];
        uint4 v1 = xb[(size_t)s1 * 16 + lane];
        uint4 v2 = xb[(size_t)s2 * 16 + lane];
        uint4 v3 = xb[(size_t)s3 * 16 + lane];
        acc[0] += (lo2f(v0.x) + lo2f(v1.x)) + (lo2f(v2.x) + lo2f(v3.x));
        acc[1] += (hi2f(v0.x) + hi2f(v1.x)) + (hi2f(v2.x) + hi2f(v3.x));
        acc[2] += (lo2f(v0.y) + lo2f(v1.y)) + (lo2f(v2.y) + lo2f(v3.y));
        acc[3] += (hi2f(v0.y) + hi2f(v1.y)) + (hi2f(v2.y) + hi2f(v3.y));
        acc[4] += (lo2f(v0.z) + lo2f(v1.z)) + (lo2f(v2.z) + lo2f(v3.z));
        acc[5] += (hi2f(v0.z) + hi2f(v1.z)) + (hi2f(v2.z) + hi2f(v3.z));
        acc[6] += (lo2f(v0.w) + lo2f(v1.w)) + (lo2f(v2.w) + lo2f(v3.w));
        acc[7] += (hi2f(v0.w) + hi2f(v1.w)) + (hi2f(v2.w) + hi2f(v3.w));
    }
    for (; e < end; ++e) {
        uint4 v0 = xb[(size_t)col[e] * 16 + lane];
        acc[0] += lo2f(v0.x); acc[1] += hi2f(v0.x);
        acc[2] += lo2f(v0.y); acc[3] += hi2f(v0.y);
        acc[4] += lo2f(v0.z); acc[5] += hi2f(v0.z);
        acc[6] += lo2f(v0.w); acc[7] += hi2f(v0.w);
    }
    float inv = 1.0f / fmaxf((float)(end - beg), 1.0f);
#pragma unroll
    for (int j = 0; j < 8; ++j) acc[j] *= inv;
    uint4 o;
    o.x = pack2(acc[0], acc[1]); o.y = pack2(acc[2], acc[3]);
    o.z = pack2(acc[4], acc[5]); o.w = pack2(acc[6], acc[7]);
    agg[(size_t)node * 16 + lane] = o;
}

// H = relu([Agg | X] @ [Wl;Wr] + bias), MFMA 16x16x32 bf16.
// Block: 128 rows, 4 waves; wave = 32 rows x 128 cols (2x8 tiles).
// A-frags: direct global uint4 (consecutive k). B-frags: prepacked Wt, one
// lane-coalesced uint4 per (c_tile, kb). No LDS, no barriers.
__global__ __launch_bounds__(256)
void sage_gemm_mfma(const unsigned short* __restrict__ Aggb,
                    const unsigned short* __restrict__ Xb,
                    const unsigned short* __restrict__ Wt,   // frag-order [8][8][64][8]
                    const float* __restrict__ bias,
                    unsigned short* __restrict__ Hb, int N) {
    const int wave = threadIdx.x >> 6;
    const int lane = threadIdx.x & 63;
    const int quad = lane >> 4;
    const int l16  = lane & 15;
    const int rowbase = blockIdx.x * 128 + wave * 32;

    floatx4 acc[2][8];
#pragma unroll
    for (int r = 0; r < 2; ++r)
#pragma unroll
        for (int c = 0; c < 8; ++c) acc[r][c] = (floatx4){0.f, 0.f, 0.f, 0.f};

    int arow0 = rowbase + l16;      if (arow0 >= N) arow0 = N - 1;
    int arow1 = rowbase + 16 + l16; if (arow1 >= N) arow1 = N - 1;
    const size_t aoff0 = (size_t)arow0 * 128 + quad * 8;
    const size_t aoff1 = (size_t)arow1 * 128 + quad * 8;

#pragma unroll
    for (int kb = 0; kb < 8; ++kb) {
        const unsigned short* Ab = (kb < 4) ? Aggb : Xb;
        const int koff = (kb & 3) * 32;
        short8 a0 = __builtin_bit_cast(short8, *(const uint4*)(Ab + aoff0 + koff));
        short8 a1 = __builtin_bit_cast(short8, *(const uint4*)(Ab + aoff1 + koff));
#pragma unroll
        for (int c = 0; c < 8; ++c) {
            short8 b = __builtin_bit_cast(short8,
                *(const uint4*)(Wt + (size_t)(((c * 8 + kb) * 64 + lane) * 8)));
            acc[0][c] = __builtin_amdgcn_mfma_f32_16x16x32_bf16(a0, b, acc[0][c], 0, 0, 0);
            acc[1][c] = __builtin_amdgcn_mfma_f32_16x16x32_bf16(a1, b, acc[1][c], 0, 0, 0);
        }
    }

    // epilogue: bias + relu + bf16 store. D: col=c*16+l16, row=+quad*4+i
    float bcol[8];
#pragma unroll
    for (int c = 0; c < 8; ++c) bcol[c] = bias[c * 16 + l16];
#pragma unroll
    for (int r = 0; r < 2; ++r)
#pragma unroll
        for (int i = 0; i < 4; ++i) {
            int row = rowbase + r * 16 + quad * 4 + i;
            if (row < N) {
#pragma unroll
                for (int c = 0; c < 8; ++c)
                    Hb[(size_t)row * 128 + c * 16 + l16] =
                        f2b(fmaxf(acc[r][c][i] + bcol[c], 0.f));
            }
        }
}

// out = [H1 | H2] @ Wot + b_out (fp32 out, 40 cols via 3 masked tiles).
__global__ __launch_bounds__(256)
void out_gemm_mfma(const unsigned short* __restrict__ H1b,
                   const unsigned short* __restrict__ H2b,
                   const unsigned short* __restrict__ Wot,  // frag-order [3][8][64][8]
                   const float* __restrict__ bo,
                   float* __restrict__ out, int N) {
    const int wave = threadIdx.x >> 6;
    const int lane = threadIdx.x & 63;
    const int quad = lane >> 4;
    const int l16  = lane & 15;
    const int rowbase = blockIdx.x * 128 + wave * 32;

    floatx4 acc[2][3];
#pragma unroll
    for (int r = 0; r < 2; ++r)
#pragma unroll
        for (int c = 0; c < 3; ++c) acc[r][c] = (floatx4){0.f, 0.f, 0.f, 0.f};

    int arow0 = rowbase + l16;      if (arow0 >= N) arow0 = N - 1;
    int arow1 = rowbase + 16 + l16; if (arow1 >= N) arow1 = N - 1;
    const size_t aoff0 = (size_t)arow0 * 128 + quad * 8;
    const size_t aoff1 = (size_t)arow1 * 128 + quad * 8;

#pragma unroll
    for (int kb = 0; kb < 8; ++kb) {
        const unsigned short* Ab = (kb < 4) ? H1b : H2b;
        const int koff = (kb & 3) * 32;
        short8 a0 = __builtin_bit_cast(short8, *(const uint4*)(Ab + aoff0 + koff));
        short8 a1 = __builtin_bit_cast(short8, *(const uint4*)(Ab + aoff1 + koff));
#pragma unroll
        for (int c = 0; c < 3; ++c) {
            short8 b = __builtin_bit_cast(short8,
                *(const uint4*)(Wot + (size_t)(((c * 8 + kb) * 64 + lane) * 8)));
            acc[0][c] = __builtin_amdgcn_mfma_f32_16x16x32_bf16(a0, b, acc[0][c], 0, 0, 0);
            acc[1][c] = __builtin_amdgcn_mfma_f32_16x16x32_bf16(a1, b, acc[1][c], 0, 0, 0);
        }
    }

    float bcol[3];
#pragma unroll
    for (int c = 0; c < 3; ++c) {
        int colc = c * 16 + l16;
        bcol[c] = (colc < 40) ? bo[colc] : 0.f;
    }
#pragma unroll
    for (int r = 0; r < 2; ++r)
#pragma unroll
        for (int i = 0; i < 4; ++i) {
            int row = rowbase + r * 16 + quad * 4 + i;
            if (row < N) {
#pragma unroll
                for (int c = 0; c < 3; ++c) {
                    int colc = c * 16 + l16;
                    if (colc < 40)
                        out[(size_t)row * 40 + colc] = acc[r][c][i] + bcol[c];
                }
            }
        }
}

extern "C" void kernel_launch(void* const* d_in, const int* in_sizes, int n_in,
                              void* d_out, int out_size, void* d_ws, size_t ws_size,
                              hipStream_t stream) {
    const float* x     = (const float*)d_in[0];
    const int*   ei1   = (const int*)d_in[1];
    const int*   ei2   = (const int*)d_in[2];
    const float* wl1   = (const float*)d_in[3];
    const float* wr1   = (const float*)d_in[4];
    const float* b1    = (const float*)d_in[5];
    const float* wl2   = (const float*)d_in[6];
    const float* wr2   = (const float*)d_in[7];
    const float* b2    = (const float*)d_in[8];
    const float* w_out = (const float*)d_in[9];
    const float* b_out = (const float*)d_in[10];

    const int N = in_sizes[0] / 128;
    const int E = in_sizes[1] / 2;

    // ---- workspace: int region | xb | h1b | h2b | aggb | wt1 | wt2 | wot
    int* deg     = (int*)d_ws;            // N
    int* fill    = deg + N;               // N
    int* row_ptr = fill + N;              // N+1
    int* bsum    = row_ptr + (N + 1);     // up to 256
    int* col     = bsum + 256;            // E
    size_t int_cnt = (size_t)(3 * N + 1 + 256) + (size_t)E;
    int_cnt = (int_cnt + 3) & ~(size_t)3;                 // 16 B align
    unsigned short* xb   = (unsigned short*)((int*)d_ws + int_cnt);
    unsigned short* h1b  = xb  + (size_t)N * 128;
    unsigned short* h2b  = h1b + (size_t)N * 128;
    unsigned short* aggb = h2b + (size_t)N * 128;
    unsigned short* wt1  = aggb + (size_t)N * 128;
    unsigned short* wt2  = wt1 + 32768;
    unsigned short* wot  = wt2 + 32768;

    const long n8         = (long)N * 128 / 8;
    const int cast_blocks = (int)((n8 + 255) / 256);
    const int nb          = (N + 1023) / 1024;
    const int edge_blocks = (E + 255) / 256;
    const int node_blocks = (N + 255) / 256;
    const int gath_blocks = (int)(((size_t)N * 16 + 255) / 256);
    const int mfma_blocks = (N + 127) / 128;

    cast_f32_b16<<<cast_blocks, 256, 0, stream>>>((const float4*)x, (uint4*)xb, n8);
    prep_weights<<<(65536 + 12288 + 255) / 256, 256, 0, stream>>>(
        wl1, wr1, wl2, wr2, w_out, wt1, wt2, wot);

    for (int layer = 0; layer < 2; ++layer) {
        const int* ei = (layer == 0) ? ei1 : ei2;
        const unsigned short* xin = (layer == 0) ? xb : h1b;
        const unsigned short* wt  = (layer == 0) ? wt1 : wt2;
        const float* bb = (layer == 0) ? b1 : b2;
        unsigned short* hout = (layer == 0) ? h1b : h2b;
        const int* srcp = ei;
        const int* dstp = ei + E;

        hipMemsetAsync(deg, 0, (size_t)2 * N * sizeof(int), stream);  // deg+fill
        degree_hist<<<edge_blocks, 256, 0, stream>>>(dstp, deg, E);
        scan1<<<nb, 256, 0, stream>>>(deg, row_ptr, bsum, N);
        scan2<<<1, 256, 0, stream>>>(bsum, nb);
        scan3<<<node_blocks, 256, 0, stream>>>(row_ptr, bsum, N, E);
        csr_fill<<<edge_blocks, 256, 0, stream>>>(srcp, dstp, row_ptr, fill, col, E);
        gather_mean_b16<<<gath_blocks, 256, 0, stream>>>((const uint4*)xin, row_ptr,
                                                         col, (uint4*)aggb, N);
        sage_gemm_mfma<<<mfma_blocks, 256, 0, stream>>>(aggb, xin, wt, bb, hout, N);
    }

    out_gemm_mfma<<<mfma_blocks, 256, 0, stream>>>(h1b, h2b, wot, b_out,
                                                   (float*)d_out, N);
}